// Round 1
// baseline (589.994 us; speedup 1.0000x reference)
//
#include <hip/hip_runtime.h>
#include <math.h>

#define BB 2
#define VV 5
#define CC 32
#define HH 128
#define WW 160
#define DD 32
#define HWp (HH*WW)          // 20480
#define NV (VV-1)            // 4 src views

// ---- workspace float offsets ----
#define OFF_RT   0                                   // B*NV*12 = 96
#define OFF_PRM  96                                  // 177 net params
#define OFF_FEAT 512                                 // V*B*HW*C = 6,553,600
#define OFF_SIM  (OFF_FEAT + VV*BB*HWp*CC)           // B*D*HW
#define OFF_SIG  (OFF_SIM + BB*DD*HWp)               // B*D*HW
#define OFF_SUM  (OFF_SIG + BB*DD*HWp)               // B*D*HW
#define OFF_WSUM (OFF_SUM + BB*DD*HWp)               // B*HW
// total = 10,527,232 floats = ~40.2 MB

// ---- output float offsets (depth, conf, prob, cost_reg, view_weights) ----
#define OUT_DEPTH 0
#define OUT_CONF  (BB*HWp)
#define OUT_PROB  (2*BB*HWp)
#define OUT_COST  (OUT_PROB + BB*DD*HWp)
#define OUT_VW    (OUT_COST + BB*DD*HWp)

// ---------------- setup: projection matrices + folded BN params ----------------
__device__ void build_proj(const float* proj, int b, int v, double M[4][4]) {
    const float* E = proj + (((b*VV + v)*2 + 0)*16);
    const float* K = proj + (((b*VV + v)*2 + 1)*16);
    for (int r = 0; r < 3; r++)
        for (int c = 0; c < 4; c++) {
            double s = 0.0;
            for (int k = 0; k < 3; k++) s += (double)K[r*4+k] * (double)E[k*4+c];
            M[r][c] = s;
        }
    for (int c = 0; c < 4; c++) M[3][c] = (double)E[12+c];
}

__device__ void inv4(const double M[4][4], double out[4][4]) {
    double a[4][8];
    for (int i = 0; i < 4; i++)
        for (int j = 0; j < 4; j++) { a[i][j] = M[i][j]; a[i][4+j] = (i == j) ? 1.0 : 0.0; }
    for (int col = 0; col < 4; col++) {
        int piv = col; double best = fabs(a[col][col]);
        for (int r = col+1; r < 4; r++) if (fabs(a[r][col]) > best) { best = fabs(a[r][col]); piv = r; }
        if (piv != col) for (int j = 0; j < 8; j++) { double t = a[col][j]; a[col][j] = a[piv][j]; a[piv][j] = t; }
        double dinv = 1.0 / a[col][col];
        for (int j = 0; j < 8; j++) a[col][j] *= dinv;
        for (int r = 0; r < 4; r++) {
            if (r == col) continue;
            double f = a[r][col];
            for (int j = 0; j < 8; j++) a[r][j] -= f * a[col][j];
        }
    }
    for (int i = 0; i < 4; i++) for (int j = 0; j < 4; j++) out[i][j] = a[i][4+j];
}

__global__ void setup_kernel(const float* __restrict__ proj,
    const float* __restrict__ w0, const float* __restrict__ g0, const float* __restrict__ b0,
    const float* __restrict__ m0, const float* __restrict__ v0,
    const float* __restrict__ w1, const float* __restrict__ g1, const float* __restrict__ b1,
    const float* __restrict__ m1, const float* __restrict__ v1,
    const float* __restrict__ w2, const float* __restrict__ b2,
    float* __restrict__ ws) {
    if (threadIdx.x != 0 || blockIdx.x != 0) return;
    for (int b = 0; b < BB; b++) {
        double refM[4][4], inv[4][4];
        build_proj(proj, b, 0, refM);
        inv4(refM, inv);
        for (int v = 1; v < VV; v++) {
            double S[4][4]; build_proj(proj, b, v, S);
            float* rt = ws + OFF_RT + (b*NV + (v-1))*12;
            for (int r = 0; r < 3; r++) {
                for (int c = 0; c < 3; c++) {
                    double s = 0.0;
                    for (int k = 0; k < 4; k++) s += S[r][k] * inv[k][c];
                    rt[r*3 + c] = (float)s;
                }
                double s = 0.0;
                for (int k = 0; k < 4; k++) s += S[r][k] * inv[k][3];
                rt[9 + r] = (float)s;
            }
        }
    }
    // folded BN params: h0 = relu(A0*s + C0); a1 = C1 + sum W1s*h0; h2 = b2 + sum W2*relu(a1)
    float* prm = ws + OFF_PRM;
    for (int o = 0; o < 16; o++) {
        float sc = g0[o] / sqrtf(v0[o] + 1e-5f);
        prm[o]      = w0[o] * sc;
        prm[16 + o] = b0[o] - m0[o] * sc;
    }
    for (int q = 0; q < 8; q++) {
        float sc = g1[q] / sqrtf(v1[q] + 1e-5f);
        for (int o = 0; o < 16; o++) prm[32 + q*16 + o] = w1[q*16 + o] * sc;
        prm[160 + q] = b1[q] - m1[q] * sc;
        prm[168 + q] = w2[q];
    }
    prm[176] = b2[0];
}

// ---------------- transpose features to (V,B,H,W,C) ----------------
__global__ __launch_bounds__(256) void transpose_kernel(const float* __restrict__ fea,
                                                        float* __restrict__ featT) {
    int t = blockIdx.x*256 + threadIdx.x;        // V*B*H*W = 204800
    int w = t % WW;
    int h = (t / WW) % HH;
    int b = (t / (WW*HH)) % BB;
    int v = t / (WW*HH*BB);
    const float* src = fea + (size_t)((v*BB + b)*CC) * HWp + h*WW + w;
    float* dst = featT + (size_t)((v*BB + b)*HWp + h*WW + w) * CC;
    #pragma unroll
    for (int c = 0; c < CC; c += 4) {
        float4 q;
        q.x = src[(c+0)*HWp];
        q.y = src[(c+1)*HWp];
        q.z = src[(c+2)*HWp];
        q.w = src[(c+3)*HWp];
        *reinterpret_cast<float4*>(dst + c) = q;
    }
}

// ---------------- warp + sim dot + pixelwise MLP (per (b,d,p)) ----------------
__global__ __launch_bounds__(256) void warp_sim_kernel(
    const float* __restrict__ featT, const float* __restrict__ rtAll,
    const float* __restrict__ prm, const float* __restrict__ depthv,
    float* __restrict__ simbuf, float* __restrict__ sigbuf, int view) {
    int p = blockIdx.x*256 + threadIdx.x;   // HW
    int d = blockIdx.y;
    int b = blockIdx.z;
    const float* rt = rtAll + (b*NV + (view-1))*12;
    float r00 = rt[0], r01 = rt[1], r02 = rt[2];
    float r10 = rt[3], r11 = rt[4], r12 = rt[5];
    float r20 = rt[6], r21 = rt[7], r22 = rt[8];
    float t0 = rt[9], t1 = rt[10], t2 = rt[11];

    int wi = p % WW, hi = p / WW;
    float fx = (float)wi, fy = (float)hi;
    float depth = depthv[(b*DD + d)*HWp + p];
    float px = (r00*fx + r01*fy + r02)*depth + t0;
    float py = (r10*fx + r11*fy + r12)*depth + t1;
    float pz = (r20*fx + r21*fy + r22)*depth + t2;
    float sx = px / pz, sy = py / pz;
    float x0f = floorf(sx), y0f = floorf(sy);
    float wx1 = sx - x0f, wy1 = sy - y0f;
    float wx0 = 1.f - wx1, wy0 = 1.f - wy1;

    bool vx0 = (x0f >= 0.f) && (x0f <= (float)(WW-1));
    bool vx1 = (x0f + 1.f >= 0.f) && (x0f + 1.f <= (float)(WW-1));
    bool vy0 = (y0f >= 0.f) && (y0f <= (float)(HH-1));
    bool vy1 = (y0f + 1.f >= 0.f) && (y0f + 1.f <= (float)(HH-1));
    float ww00 = wx0*wy0*((vx0 && vy0) ? 1.f : 0.f);
    float ww01 = wx1*wy0*((vx1 && vy0) ? 1.f : 0.f);
    float ww10 = wx0*wy1*((vx0 && vy1) ? 1.f : 0.f);
    float ww11 = wx1*wy1*((vx1 && vy1) ? 1.f : 0.f);

    int xi0 = (int)fminf(fmaxf(x0f,       0.f), (float)(WW-1));
    int xi1 = (int)fminf(fmaxf(x0f + 1.f, 0.f), (float)(WW-1));
    int yi0 = (int)fminf(fmaxf(y0f,       0.f), (float)(HH-1));
    int yi1 = (int)fminf(fmaxf(y0f + 1.f, 0.f), (float)(HH-1));
    xi0 = max(0, min(WW-1, xi0)); xi1 = max(0, min(WW-1, xi1));
    yi0 = max(0, min(HH-1, yi0)); yi1 = max(0, min(HH-1, yi1));

    int sb = (view*BB + b)*HWp;
    const float* f00 = featT + (size_t)(sb + yi0*WW + xi0) * CC;
    const float* f01 = featT + (size_t)(sb + yi0*WW + xi1) * CC;
    const float* f10 = featT + (size_t)(sb + yi1*WW + xi0) * CC;
    const float* f11 = featT + (size_t)(sb + yi1*WW + xi1) * CC;
    const float* fr  = featT + (size_t)(b*HWp + p) * CC;

    float acc = 0.f;
    #pragma unroll
    for (int c = 0; c < CC; c += 4) {
        float4 rv = *reinterpret_cast<const float4*>(fr  + c);
        float4 a  = *reinterpret_cast<const float4*>(f00 + c);
        float4 bq = *reinterpret_cast<const float4*>(f01 + c);
        float4 cq = *reinterpret_cast<const float4*>(f10 + c);
        float4 dq = *reinterpret_cast<const float4*>(f11 + c);
        acc += rv.x*(ww00*a.x + ww01*bq.x + ww10*cq.x + ww11*dq.x);
        acc += rv.y*(ww00*a.y + ww01*bq.y + ww10*cq.y + ww11*dq.y);
        acc += rv.z*(ww00*a.z + ww01*bq.z + ww10*cq.z + ww11*dq.z);
        acc += rv.w*(ww00*a.w + ww01*bq.w + ww10*cq.w + ww11*dq.w);
    }
    float sim = acc * (1.0f / (float)CC);
    int oidx = (b*DD + d)*HWp + p;
    simbuf[oidx] = sim;

    // pixelwise net (params wave-uniform -> scalar loads)
    float h0[16];
    #pragma unroll
    for (int o = 0; o < 16; o++) h0[o] = fmaxf(prm[o]*sim + prm[16+o], 0.f);
    float h2 = prm[176];
    #pragma unroll
    for (int q = 0; q < 8; q++) {
        float a1 = prm[160 + q];
        #pragma unroll
        for (int o = 0; o < 16; o++) a1 += prm[32 + q*16 + o] * h0[o];
        h2 += prm[168 + q] * fmaxf(a1, 0.f);
    }
    sigbuf[oidx] = 1.f / (1.f + expf(-h2));
}

// ---------------- per-pixel: vw = max_d sig; accumulate sums ----------------
__global__ __launch_bounds__(256) void accum_kernel(
    const float* __restrict__ simbuf, const float* __restrict__ sigbuf,
    float* __restrict__ simsum, float* __restrict__ wsum,
    float* __restrict__ out, int vi, int first) {
    int g = blockIdx.x*256 + threadIdx.x;   // B*HW
    int b = g / HWp, p = g % HWp;
    float vw = 0.f;
    #pragma unroll
    for (int d = 0; d < DD; d++) vw = fmaxf(vw, sigbuf[(b*DD + d)*HWp + p]);
    out[OUT_VW + (b*NV + vi)*HWp + p] = vw;
    float prev = first ? 1e-5f : wsum[g];
    wsum[g] = prev + vw;
    #pragma unroll
    for (int d = 0; d < DD; d++) {
        int idx = (b*DD + d)*HWp + p;
        float pv = first ? 0.f : simsum[idx];
        simsum[idx] = pv + simbuf[idx] * vw;
    }
}

// ---------------- similarity = simsum / wsum ----------------
__global__ __launch_bounds__(256) void simdiv_kernel(
    const float* __restrict__ simsum, const float* __restrict__ wsum,
    float* __restrict__ simbuf) {
    int g = blockIdx.x*256 + threadIdx.x;   // B*D*HW
    int b = g / (DD*HWp);
    int p = g % HWp;
    simbuf[g] = simsum[g] / wsum[b*HWp + p];
}

// ---------------- 3x3x3 conv (SAME, zero pad) ----------------
__global__ __launch_bounds__(256) void conv_kernel(
    const float* __restrict__ sim, const float* __restrict__ rw,
    const float* __restrict__ rb, float* __restrict__ out) {
    int g = blockIdx.x*256 + threadIdx.x;   // B*D*HW
    int p = g % HWp;
    int dt = g / HWp;
    int d = dt % DD, b = dt / DD;
    int wi = p % WW, hi = p / WW;
    float acc = rb[0];
    #pragma unroll
    for (int kd = 0; kd < 3; kd++) {
        int dd2 = d + kd - 1;
        if (dd2 < 0 || dd2 >= DD) continue;
        #pragma unroll
        for (int kh = 0; kh < 3; kh++) {
            int hh2 = hi + kh - 1;
            if (hh2 < 0 || hh2 >= HH) continue;
            #pragma unroll
            for (int kw = 0; kw < 3; kw++) {
                int ww2 = wi + kw - 1;
                if (ww2 < 0 || ww2 >= WW) continue;
                acc += rw[(kd*3 + kh)*3 + kw] * sim[((b*DD + dd2)*HH + hh2)*WW + ww2];
            }
        }
    }
    out[OUT_COST + g] = acc;
}

// ---------------- softmax over D + argmax -> depth/conf/prob ----------------
__global__ __launch_bounds__(256) void softmax_kernel(
    const float* __restrict__ depthv, float* __restrict__ out) {
    int g = blockIdx.x*256 + threadIdx.x;   // B*HW
    int b = g / HWp, p = g % HWp;
    float c[DD];
    #pragma unroll
    for (int d = 0; d < DD; d++) c[d] = out[OUT_COST + (b*DD + d)*HWp + p];
    float m = c[0]; int bi = 0;
    #pragma unroll
    for (int d = 1; d < DD; d++) { if (c[d] > m) { m = c[d]; bi = d; } }
    float e[DD]; float sum = 0.f;
    #pragma unroll
    for (int d = 0; d < DD; d++) { e[d] = expf(c[d] - m); sum += e[d]; }
    float inv = 1.f / sum;
    #pragma unroll
    for (int d = 0; d < DD; d++) out[OUT_PROB + (b*DD + d)*HWp + p] = e[d] * inv;
    out[OUT_DEPTH + g] = depthv[(b*DD + bi)*HWp + p];
    out[OUT_CONF + g]  = inv;   // max prob = exp(0)/sum
}

extern "C" void kernel_launch(void* const* d_in, const int* in_sizes, int n_in,
                              void* d_out, int out_size, void* d_ws, size_t ws_size,
                              hipStream_t stream) {
    const float* features = (const float*)d_in[0];
    const float* proj     = (const float*)d_in[1];
    const float* depthv   = (const float*)d_in[2];
    const float* w0 = (const float*)d_in[4];
    const float* g0 = (const float*)d_in[5];
    const float* b0 = (const float*)d_in[6];
    const float* m0 = (const float*)d_in[7];
    const float* v0 = (const float*)d_in[8];
    const float* w1 = (const float*)d_in[9];
    const float* g1 = (const float*)d_in[10];
    const float* b1 = (const float*)d_in[11];
    const float* m1 = (const float*)d_in[12];
    const float* v1 = (const float*)d_in[13];
    const float* w2 = (const float*)d_in[14];
    const float* b2 = (const float*)d_in[15];
    const float* rw = (const float*)d_in[16];
    const float* rb = (const float*)d_in[17];
    float* out = (float*)d_out;
    float* ws  = (float*)d_ws;

    setup_kernel<<<1, 1, 0, stream>>>(proj, w0, g0, b0, m0, v0, w1, g1, b1, m1, v1, w2, b2, ws);
    transpose_kernel<<<VV*BB*HWp/256, 256, 0, stream>>>(features, ws + OFF_FEAT);

    for (int v = 1; v < VV; v++) {
        warp_sim_kernel<<<dim3(HWp/256, DD, BB), 256, 0, stream>>>(
            ws + OFF_FEAT, ws + OFF_RT, ws + OFF_PRM, depthv,
            ws + OFF_SIM, ws + OFF_SIG, v);
        accum_kernel<<<BB*HWp/256, 256, 0, stream>>>(
            ws + OFF_SIM, ws + OFF_SIG, ws + OFF_SUM, ws + OFF_WSUM, out, v - 1, (v == 1) ? 1 : 0);
    }

    simdiv_kernel<<<BB*DD*HWp/256, 256, 0, stream>>>(ws + OFF_SUM, ws + OFF_WSUM, ws + OFF_SIM);
    conv_kernel<<<BB*DD*HWp/256, 256, 0, stream>>>(ws + OFF_SIM, rw, rb, out);
    softmax_kernel<<<BB*HWp/256, 256, 0, stream>>>(depthv, out);
}

// Round 2
// 366.857 us; speedup vs baseline: 1.6082x; 1.6082x over previous
//
#include <hip/hip_runtime.h>
#include <math.h>

#define BB 2
#define VV 5
#define CC 32
#define HH 128
#define WW 160
#define DD 32
#define HWp (HH*WW)          // 20480
#define NV (VV-1)            // 4 src views

// ---- workspace float offsets ----
#define OFF_RT   0                                   // B*NV*12 = 96
#define OFF_PRM  96                                  // 177 net params
#define OFF_FEAT 512                                 // V*B*HW*C = 6,553,600
#define OFF_SIM  (OFF_FEAT + VV*BB*HWp*CC)           // B*D*HW similarity
// total ~30 MB

// ---- output float offsets (depth, conf, prob, cost_reg, view_weights) ----
#define OUT_DEPTH 0
#define OUT_CONF  (BB*HWp)
#define OUT_PROB  (2*BB*HWp)
#define OUT_COST  (OUT_PROB + BB*DD*HWp)
#define OUT_VW    (OUT_COST + BB*DD*HWp)

// ---------------- setup: projection matrices + folded BN params ----------------
__device__ void build_proj(const float* proj, int b, int v, double M[4][4]) {
    const float* E = proj + (((b*VV + v)*2 + 0)*16);
    const float* K = proj + (((b*VV + v)*2 + 1)*16);
    for (int r = 0; r < 3; r++)
        for (int c = 0; c < 4; c++) {
            double s = 0.0;
            for (int k = 0; k < 3; k++) s += (double)K[r*4+k] * (double)E[k*4+c];
            M[r][c] = s;
        }
    for (int c = 0; c < 4; c++) M[3][c] = (double)E[12+c];
}

__device__ void inv4(const double M[4][4], double out[4][4]) {
    double a[4][8];
    for (int i = 0; i < 4; i++)
        for (int j = 0; j < 4; j++) { a[i][j] = M[i][j]; a[i][4+j] = (i == j) ? 1.0 : 0.0; }
    for (int col = 0; col < 4; col++) {
        int piv = col; double best = fabs(a[col][col]);
        for (int r = col+1; r < 4; r++) if (fabs(a[r][col]) > best) { best = fabs(a[r][col]); piv = r; }
        if (piv != col) for (int j = 0; j < 8; j++) { double t = a[col][j]; a[col][j] = a[piv][j]; a[piv][j] = t; }
        double dinv = 1.0 / a[col][col];
        for (int j = 0; j < 8; j++) a[col][j] *= dinv;
        for (int r = 0; r < 4; r++) {
            if (r == col) continue;
            double f = a[r][col];
            for (int j = 0; j < 8; j++) a[r][j] -= f * a[col][j];
        }
    }
    for (int i = 0; i < 4; i++) for (int j = 0; j < 4; j++) out[i][j] = a[i][4+j];
}

__global__ void setup_kernel(const float* __restrict__ proj,
    const float* __restrict__ w0, const float* __restrict__ g0, const float* __restrict__ b0,
    const float* __restrict__ m0, const float* __restrict__ v0,
    const float* __restrict__ w1, const float* __restrict__ g1, const float* __restrict__ b1,
    const float* __restrict__ m1, const float* __restrict__ v1,
    const float* __restrict__ w2, const float* __restrict__ b2,
    float* __restrict__ ws) {
    if (threadIdx.x != 0 || blockIdx.x != 0) return;
    for (int b = 0; b < BB; b++) {
        double refM[4][4], inv[4][4];
        build_proj(proj, b, 0, refM);
        inv4(refM, inv);
        for (int v = 1; v < VV; v++) {
            double S[4][4]; build_proj(proj, b, v, S);
            float* rt = ws + OFF_RT + (b*NV + (v-1))*12;
            for (int r = 0; r < 3; r++) {
                for (int c = 0; c < 3; c++) {
                    double s = 0.0;
                    for (int k = 0; k < 4; k++) s += S[r][k] * inv[k][c];
                    rt[r*3 + c] = (float)s;
                }
                double s = 0.0;
                for (int k = 0; k < 4; k++) s += S[r][k] * inv[k][3];
                rt[9 + r] = (float)s;
            }
        }
    }
    float* prm = ws + OFF_PRM;
    for (int o = 0; o < 16; o++) {
        float sc = g0[o] / sqrtf(v0[o] + 1e-5f);
        prm[o]      = w0[o] * sc;
        prm[16 + o] = b0[o] - m0[o] * sc;
    }
    for (int q = 0; q < 8; q++) {
        float sc = g1[q] / sqrtf(v1[q] + 1e-5f);
        for (int o = 0; o < 16; o++) prm[32 + q*16 + o] = w1[q*16 + o] * sc;
        prm[160 + q] = b1[q] - m1[q] * sc;
        prm[168 + q] = w2[q];
    }
    prm[176] = b2[0];
}

// ---------------- transpose features to (V,B,H,W,C) ----------------
__global__ __launch_bounds__(256) void transpose_kernel(const float* __restrict__ fea,
                                                        float* __restrict__ featT) {
    int t = blockIdx.x*256 + threadIdx.x;        // V*B*H*W
    int w = t % WW;
    int h = (t / WW) % HH;
    int b = (t / (WW*HH)) % BB;
    int v = t / (WW*HH*BB);
    const float* src = fea + (size_t)((v*BB + b)*CC) * HWp + h*WW + w;
    float* dst = featT + (size_t)((v*BB + b)*HWp + h*WW + w) * CC;
    #pragma unroll
    for (int c = 0; c < CC; c += 4) {
        float4 q;
        q.x = src[(c+0)*HWp];
        q.y = src[(c+1)*HWp];
        q.z = src[(c+2)*HWp];
        q.w = src[(c+3)*HWp];
        *reinterpret_cast<float4*>(dst + c) = q;
    }
}

__device__ __forceinline__ float half_sum(float v) {
    v += __shfl_xor(v, 1);
    v += __shfl_xor(v, 2);
    v += __shfl_xor(v, 4);
    v += __shfl_xor(v, 8);
    v += __shfl_xor(v, 16);
    return v;
}
__device__ __forceinline__ float half_max(float v) {
    v = fmaxf(v, __shfl_xor(v, 1));
    v = fmaxf(v, __shfl_xor(v, 2));
    v = fmaxf(v, __shfl_xor(v, 4));
    v = fmaxf(v, __shfl_xor(v, 8));
    v = fmaxf(v, __shfl_xor(v, 16));
    return v;
}

__device__ __forceinline__ float mlp_sig(const float* __restrict__ prm, float s) {
    float h0[16];
    #pragma unroll
    for (int o = 0; o < 16; o++) h0[o] = fmaxf(prm[o]*s + prm[16+o], 0.f);
    float h2 = prm[176];
    #pragma unroll
    for (int q = 0; q < 8; q++) {
        float a1 = prm[160+q];
        #pragma unroll
        for (int o = 0; o < 16; o++) a1 += prm[32+q*16+o]*h0[o];
        h2 += prm[168+q]*fmaxf(a1, 0.f);
    }
    return 1.f/(1.f + expf(-h2));
}

// ---------------- fused warp + sim + MLP + view aggregation ----------------
// block = 256 threads = 4 waves = 8 pixels. Phase A: lane=channel, per-wave 2 pixels,
// loop over D with coalesced tap loads. Phase B: thread=(pixel,d), MLP + vw + aggregate.
__global__ __launch_bounds__(256) void fused_sim_kernel(
    const float* __restrict__ featT, const float* __restrict__ rtAll,
    const float* __restrict__ prm, const float* __restrict__ depthv,
    float* __restrict__ simout, float* __restrict__ out) {
    __shared__ float simL[NV][8][DD];      // 4 KB
    __shared__ float pk[256*8];            // 8 KB: per-(pix,d) packet: 4 addr + 4 weights

    int t = threadIdx.x;
    int lane32 = t & 31;
    int half   = (t >> 5) & 1;
    int wave   = t >> 6;
    int pixA   = wave*2 + half;            // phase-A pixel owned by this half-wave
    int b = blockIdx.y;
    int pA = blockIdx.x*8 + pixA;
    int wiA = pA % WW, hiA = pA / WW;
    float fx = (float)wiA, fy = (float)hiA;

    // coord-role: this thread computes coords for depth d=lane32 of pixel pixA
    float myD  = depthv[(b*DD + lane32)*HWp + pA];
    // channel-role: lane32 = channel c of pixel pixA
    float refv = featT[(size_t)(b*HWp + pA)*CC + lane32];

    #pragma unroll
    for (int v = 1; v < VV; v++) {
        const float* rt = rtAll + (b*NV + (v-1))*12;
        float bx = rt[0]*fx + rt[1]*fy + rt[2];
        float by = rt[3]*fx + rt[4]*fy + rt[5];
        float bz = rt[6]*fx + rt[7]*fy + rt[8];
        float px = bx*myD + rt[9];
        float py = by*myD + rt[10];
        float pz = bz*myD + rt[11];
        float sx = px / pz, sy = py / pz;
        float x0f = floorf(sx), y0f = floorf(sy);
        float wx1 = sx - x0f, wy1 = sy - y0f;
        float wx0 = 1.f - wx1, wy0 = 1.f - wy1;
        bool vx0 = (x0f >= 0.f) && (x0f <= (float)(WW-1));
        bool vx1 = (x0f + 1.f >= 0.f) && (x0f + 1.f <= (float)(WW-1));
        bool vy0 = (y0f >= 0.f) && (y0f <= (float)(HH-1));
        bool vy1 = (y0f + 1.f >= 0.f) && (y0f + 1.f <= (float)(HH-1));
        float ww00 = wx0*wy0*((vx0 && vy0) ? 1.f : 0.f);
        float ww01 = wx1*wy0*((vx1 && vy0) ? 1.f : 0.f);
        float ww10 = wx0*wy1*((vx0 && vy1) ? 1.f : 0.f);
        float ww11 = wx1*wy1*((vx1 && vy1) ? 1.f : 0.f);
        int xi0 = (int)fminf(fmaxf(x0f,       0.f), (float)(WW-1));
        int xi1 = (int)fminf(fmaxf(x0f + 1.f, 0.f), (float)(WW-1));
        int yi0 = (int)fminf(fmaxf(y0f,       0.f), (float)(HH-1));
        int yi1 = (int)fminf(fmaxf(y0f + 1.f, 0.f), (float)(HH-1));
        int sb = (v*BB + b)*HWp*CC;
        int a00 = sb + (yi0*WW + xi0)*CC;
        int a01 = sb + (yi0*WW + xi1)*CC;
        int a10 = sb + (yi1*WW + xi0)*CC;
        int a11 = sb + (yi1*WW + xi1)*CC;
        float4 p0, p1;
        p0.x = __int_as_float(a00); p0.y = __int_as_float(a01);
        p0.z = __int_as_float(a10); p0.w = __int_as_float(a11);
        p1.x = ww00; p1.y = ww01; p1.z = ww10; p1.w = ww11;
        *reinterpret_cast<float4*>(&pk[t*8])     = p0;
        *reinterpret_cast<float4*>(&pk[t*8 + 4]) = p1;
        // same-wave produce/consume (no barrier needed): reader below reads
        // pk[(pixA*32+d)*8] which was written by this wave's own lanes.
        #pragma unroll 4
        for (int d = 0; d < DD; d++) {
            float4 A  = *reinterpret_cast<const float4*>(&pk[(pixA*32 + d)*8]);
            float4 Wt = *reinterpret_cast<const float4*>(&pk[(pixA*32 + d)*8 + 4]);
            float t00 = featT[__float_as_int(A.x) + lane32];
            float t01 = featT[__float_as_int(A.y) + lane32];
            float t10 = featT[__float_as_int(A.z) + lane32];
            float t11 = featT[__float_as_int(A.w) + lane32];
            float val = refv * (Wt.x*t00 + Wt.y*t01 + Wt.z*t10 + Wt.w*t11);
            val = half_sum(val);
            if (lane32 == 0) simL[v-1][pixA][d] = val * (1.f/(float)CC);
        }
    }
    __syncthreads();

    // ---- phase B: thread = (pixel pixB, depth dB) ----
    int pixB = t >> 5;      // 0..7
    int dB   = t & 31;
    int pB = blockIdx.x*8 + pixB;

    float s0 = simL[0][pixB][dB];
    float s1 = simL[1][pixB][dB];
    float s2 = simL[2][pixB][dB];
    float s3 = simL[3][pixB][dB];

    float vw0 = half_max(mlp_sig(prm, s0));
    float vw1 = half_max(mlp_sig(prm, s1));
    float vw2 = half_max(mlp_sig(prm, s2));
    float vw3 = half_max(mlp_sig(prm, s3));

    if (dB == 0) out[OUT_VW + (b*NV + 0)*HWp + pB] = vw0;
    if (dB == 1) out[OUT_VW + (b*NV + 1)*HWp + pB] = vw1;
    if (dB == 2) out[OUT_VW + (b*NV + 2)*HWp + pB] = vw2;
    if (dB == 3) out[OUT_VW + (b*NV + 3)*HWp + pB] = vw3;

    float wsum = 1e-5f + vw0 + vw1 + vw2 + vw3;
    float ssum = s0*vw0 + s1*vw1 + s2*vw2 + s3*vw3;
    simout[(b*DD + dB)*HWp + pB] = ssum / wsum;
}

// ---------------- 3x3x3 conv (SAME, zero pad) ----------------
__global__ __launch_bounds__(256) void conv_kernel(
    const float* __restrict__ sim, const float* __restrict__ rw,
    const float* __restrict__ rb, float* __restrict__ out) {
    int g = blockIdx.x*256 + threadIdx.x;   // B*D*HW
    int p = g % HWp;
    int dt = g / HWp;
    int d = dt % DD, b = dt / DD;
    int wi = p % WW, hi = p / WW;
    float acc = rb[0];
    #pragma unroll
    for (int kd = 0; kd < 3; kd++) {
        int dd2 = d + kd - 1;
        if (dd2 < 0 || dd2 >= DD) continue;
        #pragma unroll
        for (int kh = 0; kh < 3; kh++) {
            int hh2 = hi + kh - 1;
            if (hh2 < 0 || hh2 >= HH) continue;
            #pragma unroll
            for (int kw = 0; kw < 3; kw++) {
                int ww2 = wi + kw - 1;
                if (ww2 < 0 || ww2 >= WW) continue;
                acc += rw[(kd*3 + kh)*3 + kw] * sim[((b*DD + dd2)*HH + hh2)*WW + ww2];
            }
        }
    }
    out[OUT_COST + g] = acc;
}

// ---------------- softmax over D + argmax -> depth/conf/prob ----------------
__global__ __launch_bounds__(256) void softmax_kernel(
    const float* __restrict__ depthv, float* __restrict__ out) {
    int g = blockIdx.x*256 + threadIdx.x;   // B*HW
    int b = g / HWp, p = g % HWp;
    float c[DD];
    #pragma unroll
    for (int d = 0; d < DD; d++) c[d] = out[OUT_COST + (b*DD + d)*HWp + p];
    float m = c[0]; int bi = 0;
    #pragma unroll
    for (int d = 1; d < DD; d++) { if (c[d] > m) { m = c[d]; bi = d; } }
    float e[DD]; float sum = 0.f;
    #pragma unroll
    for (int d = 0; d < DD; d++) { e[d] = expf(c[d] - m); sum += e[d]; }
    float inv = 1.f / sum;
    #pragma unroll
    for (int d = 0; d < DD; d++) out[OUT_PROB + (b*DD + d)*HWp + p] = e[d] * inv;
    out[OUT_DEPTH + g] = depthv[(b*DD + bi)*HWp + p];
    out[OUT_CONF + g]  = inv;
}

extern "C" void kernel_launch(void* const* d_in, const int* in_sizes, int n_in,
                              void* d_out, int out_size, void* d_ws, size_t ws_size,
                              hipStream_t stream) {
    const float* features = (const float*)d_in[0];
    const float* proj     = (const float*)d_in[1];
    const float* depthv   = (const float*)d_in[2];
    const float* w0 = (const float*)d_in[4];
    const float* g0 = (const float*)d_in[5];
    const float* b0 = (const float*)d_in[6];
    const float* m0 = (const float*)d_in[7];
    const float* v0 = (const float*)d_in[8];
    const float* w1 = (const float*)d_in[9];
    const float* g1 = (const float*)d_in[10];
    const float* b1 = (const float*)d_in[11];
    const float* m1 = (const float*)d_in[12];
    const float* v1 = (const float*)d_in[13];
    const float* w2 = (const float*)d_in[14];
    const float* b2 = (const float*)d_in[15];
    const float* rw = (const float*)d_in[16];
    const float* rb = (const float*)d_in[17];
    float* out = (float*)d_out;
    float* ws  = (float*)d_ws;

    setup_kernel<<<1, 1, 0, stream>>>(proj, w0, g0, b0, m0, v0, w1, g1, b1, m1, v1, w2, b2, ws);
    transpose_kernel<<<VV*BB*HWp/256, 256, 0, stream>>>(features, ws + OFF_FEAT);

    fused_sim_kernel<<<dim3(HWp/8, BB), 256, 0, stream>>>(
        ws + OFF_FEAT, ws + OFF_RT, ws + OFF_PRM, depthv,
        ws + OFF_SIM, out);

    conv_kernel<<<BB*DD*HWp/256, 256, 0, stream>>>(ws + OFF_SIM, rw, rb, out);
    softmax_kernel<<<BB*HWp/256, 256, 0, stream>>>(depthv, out);
}

// Round 3
// 249.110 us; speedup vs baseline: 2.3684x; 1.4727x over previous
//
#include <hip/hip_runtime.h>
#include <math.h>

#define BB 2
#define VV 5
#define CC 32
#define HH 128
#define WW 160
#define DD 32
#define HWp (HH*WW)          // 20480
#define NV (VV-1)            // 4 src views

// ---- workspace float offsets ----
#define OFF_RT   0                                   // B*NV*12 = 96
#define OFF_PRM  96                                  // 177 net params
#define OFF_FEAT 512                                 // V*B*HW*C = 6,553,600
#define OFF_SIM  (OFF_FEAT + VV*BB*HWp*CC)           // B*D*HW similarity

// ---- output float offsets (depth, conf, prob, cost_reg, view_weights) ----
#define OUT_DEPTH 0
#define OUT_CONF  (BB*HWp)
#define OUT_PROB  (2*BB*HWp)
#define OUT_COST  (OUT_PROB + BB*DD*HWp)
#define OUT_VW    (OUT_COST + BB*DD*HWp)

// ---------------- setup: projection matrices + folded BN params ----------------
__device__ void build_proj(const float* proj, int b, int v, double M[4][4]) {
    const float* E = proj + (((b*VV + v)*2 + 0)*16);
    const float* K = proj + (((b*VV + v)*2 + 1)*16);
    for (int r = 0; r < 3; r++)
        for (int c = 0; c < 4; c++) {
            double s = 0.0;
            for (int k = 0; k < 3; k++) s += (double)K[r*4+k] * (double)E[k*4+c];
            M[r][c] = s;
        }
    for (int c = 0; c < 4; c++) M[3][c] = (double)E[12+c];
}

__device__ void inv4(const double M[4][4], double out[4][4]) {
    double a[4][8];
    for (int i = 0; i < 4; i++)
        for (int j = 0; j < 4; j++) { a[i][j] = M[i][j]; a[i][4+j] = (i == j) ? 1.0 : 0.0; }
    for (int col = 0; col < 4; col++) {
        int piv = col; double best = fabs(a[col][col]);
        for (int r = col+1; r < 4; r++) if (fabs(a[r][col]) > best) { best = fabs(a[r][col]); piv = r; }
        if (piv != col) for (int j = 0; j < 8; j++) { double t = a[col][j]; a[col][j] = a[piv][j]; a[piv][j] = t; }
        double dinv = 1.0 / a[col][col];
        for (int j = 0; j < 8; j++) a[col][j] *= dinv;
        for (int r = 0; r < 4; r++) {
            if (r == col) continue;
            double f = a[r][col];
            for (int j = 0; j < 8; j++) a[r][j] -= f * a[col][j];
        }
    }
    for (int i = 0; i < 4; i++) for (int j = 0; j < 4; j++) out[i][j] = a[i][4+j];
}

__global__ void setup_kernel(const float* __restrict__ proj,
    const float* __restrict__ w0, const float* __restrict__ g0, const float* __restrict__ b0,
    const float* __restrict__ m0, const float* __restrict__ v0,
    const float* __restrict__ w1, const float* __restrict__ g1, const float* __restrict__ b1,
    const float* __restrict__ m1, const float* __restrict__ v1,
    const float* __restrict__ w2, const float* __restrict__ b2,
    float* __restrict__ ws) {
    if (threadIdx.x != 0 || blockIdx.x != 0) return;
    for (int b = 0; b < BB; b++) {
        double refM[4][4], inv[4][4];
        build_proj(proj, b, 0, refM);
        inv4(refM, inv);
        for (int v = 1; v < VV; v++) {
            double S[4][4]; build_proj(proj, b, v, S);
            float* rt = ws + OFF_RT + (b*NV + (v-1))*12;
            for (int r = 0; r < 3; r++) {
                for (int c = 0; c < 3; c++) {
                    double s = 0.0;
                    for (int k = 0; k < 4; k++) s += S[r][k] * inv[k][c];
                    rt[r*3 + c] = (float)s;
                }
                double s = 0.0;
                for (int k = 0; k < 4; k++) s += S[r][k] * inv[k][3];
                rt[9 + r] = (float)s;
            }
        }
    }
    float* prm = ws + OFF_PRM;
    for (int o = 0; o < 16; o++) {
        float sc = g0[o] / sqrtf(v0[o] + 1e-5f);
        prm[o]      = w0[o] * sc;
        prm[16 + o] = b0[o] - m0[o] * sc;
    }
    for (int q = 0; q < 8; q++) {
        float sc = g1[q] / sqrtf(v1[q] + 1e-5f);
        for (int o = 0; o < 16; o++) prm[32 + q*16 + o] = w1[q*16 + o] * sc;
        prm[160 + q] = b1[q] - m1[q] * sc;
        prm[168 + q] = w2[q];
    }
    prm[176] = b2[0];
}

// ---------------- transpose features to (V,B,H,W,C) ----------------
__global__ __launch_bounds__(256) void transpose_kernel(const float* __restrict__ fea,
                                                        float* __restrict__ featT) {
    int t = blockIdx.x*256 + threadIdx.x;        // V*B*H*W
    int w = t % WW;
    int h = (t / WW) % HH;
    int b = (t / (WW*HH)) % BB;
    int v = t / (WW*HH*BB);
    const float* src = fea + (size_t)((v*BB + b)*CC) * HWp + h*WW + w;
    float* dst = featT + (size_t)((v*BB + b)*HWp + h*WW + w) * CC;
    #pragma unroll
    for (int c = 0; c < CC; c += 4) {
        float4 q;
        q.x = src[(c+0)*HWp];
        q.y = src[(c+1)*HWp];
        q.z = src[(c+2)*HWp];
        q.w = src[(c+3)*HWp];
        *reinterpret_cast<float4*>(dst + c) = q;
    }
}

__device__ __forceinline__ float half_max(float v) {
    v = fmaxf(v, __shfl_xor(v, 1));
    v = fmaxf(v, __shfl_xor(v, 2));
    v = fmaxf(v, __shfl_xor(v, 4));
    v = fmaxf(v, __shfl_xor(v, 8));
    v = fmaxf(v, __shfl_xor(v, 16));
    return v;
}

__device__ __forceinline__ float mlp_sig(const float* __restrict__ prm, float s) {
    float h0[16];
    #pragma unroll
    for (int o = 0; o < 16; o++) h0[o] = fmaxf(prm[o]*s + prm[16+o], 0.f);
    float h2 = prm[176];
    #pragma unroll
    for (int q = 0; q < 8; q++) {
        float a1 = prm[160+q];
        #pragma unroll
        for (int o = 0; o < 16; o++) a1 += prm[32+q*16+o]*h0[o];
        h2 += prm[168+q]*fmaxf(a1, 0.f);
    }
    return 1.f/(1.f + expf(-h2));
}

// ---------------- fused warp + sim + MLP + view aggregation ----------------
// block = 256 threads: phase A thread=(d=t>>3, channel-quad=t&7), loop over 32
// pixels of one row segment; all 32 depths in flight per pixel, taps are single
// 128B lines shared by 8 sub-lanes. Phase B: thread=(pixel,d) MLP + aggregate.
__global__ __launch_bounds__(256) void fused_sim_kernel(
    const float* __restrict__ featT, const float* __restrict__ rtAll,
    const float* __restrict__ prm, const float* __restrict__ depthv,
    float* __restrict__ simout, float* __restrict__ out) {
    __shared__ float simL[NV][DD][33];     // padded: conflict-free

    int t = threadIdx.x;
    int dB  = t >> 3;     // 0..31 depth
    int sub = t & 7;      // channel quad: channels sub*4 .. sub*4+3
    int b = blockIdx.y;
    int pbase = blockIdx.x * 32;           // 32-pixel row segment (32 | 160)
    int hi  = pbase / WW;
    int wi0 = pbase % WW;
    float fy = (float)hi;

    // wave-uniform projection coefficients (compiler -> s_load)
    float rc[NV][12];
    #pragma unroll
    for (int v = 0; v < NV; v++)
        #pragma unroll
        for (int j = 0; j < 12; j++)
            rc[v][j] = rtAll[(b*NV + v)*12 + j];

    #pragma unroll 2
    for (int k = 0; k < 32; k++) {
        int p = pbase + k;
        float fx = (float)(wi0 + k);
        float depth = depthv[(b*DD + dB)*HWp + p];
        const float4 rv = *reinterpret_cast<const float4*>(
            featT + (size_t)(b*HWp + p)*CC + sub*4);

        #pragma unroll
        for (int v = 0; v < NV; v++) {
            float px = (rc[v][0]*fx + rc[v][1]*fy + rc[v][2])*depth + rc[v][9];
            float py = (rc[v][3]*fx + rc[v][4]*fy + rc[v][5])*depth + rc[v][10];
            float pz = (rc[v][6]*fx + rc[v][7]*fy + rc[v][8])*depth + rc[v][11];
            float zi = 1.f / pz;
            float sx = px * zi, sy = py * zi;
            float x0f = floorf(sx), y0f = floorf(sy);
            float wx1 = sx - x0f, wy1 = sy - y0f;
            float wx0 = 1.f - wx1, wy0 = 1.f - wy1;
            bool vx0 = (x0f >= 0.f) && (x0f <= (float)(WW-1));
            bool vx1 = (x0f + 1.f >= 0.f) && (x0f + 1.f <= (float)(WW-1));
            bool vy0 = (y0f >= 0.f) && (y0f <= (float)(HH-1));
            bool vy1 = (y0f + 1.f >= 0.f) && (y0f + 1.f <= (float)(HH-1));
            float ww00 = wx0*wy0*((vx0 && vy0) ? 1.f : 0.f);
            float ww01 = wx1*wy0*((vx1 && vy0) ? 1.f : 0.f);
            float ww10 = wx0*wy1*((vx0 && vy1) ? 1.f : 0.f);
            float ww11 = wx1*wy1*((vx1 && vy1) ? 1.f : 0.f);
            int xi0 = (int)fminf(fmaxf(x0f,       0.f), (float)(WW-1));
            int xi1 = (int)fminf(fmaxf(x0f + 1.f, 0.f), (float)(WW-1));
            int yi0 = (int)fminf(fmaxf(y0f,       0.f), (float)(HH-1));
            int yi1 = (int)fminf(fmaxf(y0f + 1.f, 0.f), (float)(HH-1));
            int sb = ((v+1)*BB + b)*HWp*CC;
            const float* base = featT + sb + sub*4;
            float4 t00 = *reinterpret_cast<const float4*>(base + (yi0*WW + xi0)*CC);
            float4 t01 = *reinterpret_cast<const float4*>(base + (yi0*WW + xi1)*CC);
            float4 t10 = *reinterpret_cast<const float4*>(base + (yi1*WW + xi0)*CC);
            float4 t11 = *reinterpret_cast<const float4*>(base + (yi1*WW + xi1)*CC);
            float blx = ww00*t00.x + ww01*t01.x + ww10*t10.x + ww11*t11.x;
            float bly = ww00*t00.y + ww01*t01.y + ww10*t10.y + ww11*t11.y;
            float blz = ww00*t00.z + ww01*t01.z + ww10*t10.z + ww11*t11.z;
            float blw = ww00*t00.w + ww01*t01.w + ww10*t10.w + ww11*t11.w;
            float val = rv.x*blx + rv.y*bly + rv.z*blz + rv.w*blw;
            val += __shfl_xor(val, 1);
            val += __shfl_xor(val, 2);
            val += __shfl_xor(val, 4);
            if (sub == 0) simL[v][dB][k] = val * (1.f/(float)CC);
        }
    }
    __syncthreads();

    // ---- phase B: thread = (pixel p8, depth d2), 4 pixel-group iterations ----
    int p8 = t >> 5;      // 0..7
    int d2 = t & 31;
    #pragma unroll
    for (int pi = 0; pi < 4; pi++) {
        int pidx = pi*8 + p8;
        int p = pbase + pidx;
        float s0 = simL[0][d2][pidx];
        float s1 = simL[1][d2][pidx];
        float s2 = simL[2][d2][pidx];
        float s3 = simL[3][d2][pidx];

        float vw0 = half_max(mlp_sig(prm, s0));
        float vw1 = half_max(mlp_sig(prm, s1));
        float vw2 = half_max(mlp_sig(prm, s2));
        float vw3 = half_max(mlp_sig(prm, s3));

        if (d2 == 0) out[OUT_VW + (b*NV + 0)*HWp + p] = vw0;
        if (d2 == 1) out[OUT_VW + (b*NV + 1)*HWp + p] = vw1;
        if (d2 == 2) out[OUT_VW + (b*NV + 2)*HWp + p] = vw2;
        if (d2 == 3) out[OUT_VW + (b*NV + 3)*HWp + p] = vw3;

        float wsum = 1e-5f + vw0 + vw1 + vw2 + vw3;
        float ssum = s0*vw0 + s1*vw1 + s2*vw2 + s3*vw3;
        simout[(b*DD + d2)*HWp + p] = ssum / wsum;
    }
}

// ---------------- 3x3x3 conv (SAME, zero pad) ----------------
__global__ __launch_bounds__(256) void conv_kernel(
    const float* __restrict__ sim, const float* __restrict__ rw,
    const float* __restrict__ rb, float* __restrict__ out) {
    int g = blockIdx.x*256 + threadIdx.x;   // B*D*HW
    int p = g % HWp;
    int dt = g / HWp;
    int d = dt % DD, b = dt / DD;
    int wi = p % WW, hi = p / WW;
    float acc = rb[0];
    #pragma unroll
    for (int kd = 0; kd < 3; kd++) {
        int dd2 = d + kd - 1;
        if (dd2 < 0 || dd2 >= DD) continue;
        #pragma unroll
        for (int kh = 0; kh < 3; kh++) {
            int hh2 = hi + kh - 1;
            if (hh2 < 0 || hh2 >= HH) continue;
            #pragma unroll
            for (int kw = 0; kw < 3; kw++) {
                int ww2 = wi + kw - 1;
                if (ww2 < 0 || ww2 >= WW) continue;
                acc += rw[(kd*3 + kh)*3 + kw] * sim[((b*DD + dd2)*HH + hh2)*WW + ww2];
            }
        }
    }
    out[OUT_COST + g] = acc;
}

// ---------------- softmax over D + argmax -> depth/conf/prob ----------------
__global__ __launch_bounds__(256) void softmax_kernel(
    const float* __restrict__ depthv, float* __restrict__ out) {
    int g = blockIdx.x*256 + threadIdx.x;   // B*HW
    int b = g / HWp, p = g % HWp;
    float c[DD];
    #pragma unroll
    for (int d = 0; d < DD; d++) c[d] = out[OUT_COST + (b*DD + d)*HWp + p];
    float m = c[0]; int bi = 0;
    #pragma unroll
    for (int d = 1; d < DD; d++) { if (c[d] > m) { m = c[d]; bi = d; } }
    float e[DD]; float sum = 0.f;
    #pragma unroll
    for (int d = 0; d < DD; d++) { e[d] = expf(c[d] - m); sum += e[d]; }
    float inv = 1.f / sum;
    #pragma unroll
    for (int d = 0; d < DD; d++) out[OUT_PROB + (b*DD + d)*HWp + p] = e[d] * inv;
    out[OUT_DEPTH + g] = depthv[(b*DD + bi)*HWp + p];
    out[OUT_CONF + g]  = inv;
}

extern "C" void kernel_launch(void* const* d_in, const int* in_sizes, int n_in,
                              void* d_out, int out_size, void* d_ws, size_t ws_size,
                              hipStream_t stream) {
    const float* features = (const float*)d_in[0];
    const float* proj     = (const float*)d_in[1];
    const float* depthv   = (const float*)d_in[2];
    const float* w0 = (const float*)d_in[4];
    const float* g0 = (const float*)d_in[5];
    const float* b0 = (const float*)d_in[6];
    const float* m0 = (const float*)d_in[7];
    const float* v0 = (const float*)d_in[8];
    const float* w1 = (const float*)d_in[9];
    const float* g1 = (const float*)d_in[10];
    const float* b1 = (const float*)d_in[11];
    const float* m1 = (const float*)d_in[12];
    const float* v1 = (const float*)d_in[13];
    const float* w2 = (const float*)d_in[14];
    const float* b2 = (const float*)d_in[15];
    const float* rw = (const float*)d_in[16];
    const float* rb = (const float*)d_in[17];
    float* out = (float*)d_out;
    float* ws  = (float*)d_ws;

    setup_kernel<<<1, 1, 0, stream>>>(proj, w0, g0, b0, m0, v0, w1, g1, b1, m1, v1, w2, b2, ws);
    transpose_kernel<<<VV*BB*HWp/256, 256, 0, stream>>>(features, ws + OFF_FEAT);

    fused_sim_kernel<<<dim3(HWp/32, BB), 256, 0, stream>>>(
        ws + OFF_FEAT, ws + OFF_RT, ws + OFF_PRM, depthv,
        ws + OFF_SIM, out);

    conv_kernel<<<BB*DD*HWp/256, 256, 0, stream>>>(ws + OFF_SIM, rw, rb, out);
    softmax_kernel<<<BB*HWp/256, 256, 0, stream>>>(depthv, out);
}

// Round 4
// 197.079 us; speedup vs baseline: 2.9937x; 1.2640x over previous
//
#include <hip/hip_runtime.h>
#include <math.h>

#define BB 2
#define VV 5
#define CC 32
#define HH 128
#define WW 160
#define DD 32
#define HWp (HH*WW)          // 20480
#define NV (VV-1)            // 4 src views
#define PX 16                // pixels per block (divides WW)

// ---- workspace float offsets ----
#define OFF_RT   0                                   // B*NV*12 = 96
#define OFF_PRM  96                                  // 177 net params
#define OFF_FEAT 512                                 // V*B*HW*C = 6,553,600
#define OFF_SIM  (OFF_FEAT + VV*BB*HWp*CC)           // B*D*HW similarity

// ---- output float offsets (depth, conf, prob, cost_reg, view_weights) ----
#define OUT_DEPTH 0
#define OUT_CONF  (BB*HWp)
#define OUT_PROB  (2*BB*HWp)
#define OUT_COST  (OUT_PROB + BB*DD*HWp)
#define OUT_VW    (OUT_COST + BB*DD*HWp)

// ---------------- setup: projection matrices + folded BN params ----------------
__device__ void build_proj(const float* proj, int b, int v, double M[4][4]) {
    const float* E = proj + (((b*VV + v)*2 + 0)*16);
    const float* K = proj + (((b*VV + v)*2 + 1)*16);
    for (int r = 0; r < 3; r++)
        for (int c = 0; c < 4; c++) {
            double s = 0.0;
            for (int k = 0; k < 3; k++) s += (double)K[r*4+k] * (double)E[k*4+c];
            M[r][c] = s;
        }
    for (int c = 0; c < 4; c++) M[3][c] = (double)E[12+c];
}

__device__ void inv4(const double M[4][4], double out[4][4]) {
    double a[4][8];
    for (int i = 0; i < 4; i++)
        for (int j = 0; j < 4; j++) { a[i][j] = M[i][j]; a[i][4+j] = (i == j) ? 1.0 : 0.0; }
    for (int col = 0; col < 4; col++) {
        int piv = col; double best = fabs(a[col][col]);
        for (int r = col+1; r < 4; r++) if (fabs(a[r][col]) > best) { best = fabs(a[r][col]); piv = r; }
        if (piv != col) for (int j = 0; j < 8; j++) { double t = a[col][j]; a[col][j] = a[piv][j]; a[piv][j] = t; }
        double dinv = 1.0 / a[col][col];
        for (int j = 0; j < 8; j++) a[col][j] *= dinv;
        for (int r = 0; r < 4; r++) {
            if (r == col) continue;
            double f = a[r][col];
            for (int j = 0; j < 8; j++) a[r][j] -= f * a[col][j];
        }
    }
    for (int i = 0; i < 4; i++) for (int j = 0; j < 4; j++) out[i][j] = a[i][4+j];
}

__global__ void setup_kernel(const float* __restrict__ proj,
    const float* __restrict__ w0, const float* __restrict__ g0, const float* __restrict__ b0,
    const float* __restrict__ m0, const float* __restrict__ v0,
    const float* __restrict__ w1, const float* __restrict__ g1, const float* __restrict__ b1,
    const float* __restrict__ m1, const float* __restrict__ v1,
    const float* __restrict__ w2, const float* __restrict__ b2,
    float* __restrict__ ws) {
    if (threadIdx.x != 0 || blockIdx.x != 0) return;
    for (int b = 0; b < BB; b++) {
        double refM[4][4], inv[4][4];
        build_proj(proj, b, 0, refM);
        inv4(refM, inv);
        for (int v = 1; v < VV; v++) {
            double S[4][4]; build_proj(proj, b, v, S);
            float* rt = ws + OFF_RT + (b*NV + (v-1))*12;
            for (int r = 0; r < 3; r++) {
                for (int c = 0; c < 3; c++) {
                    double s = 0.0;
                    for (int k = 0; k < 4; k++) s += S[r][k] * inv[k][c];
                    rt[r*3 + c] = (float)s;
                }
                double s = 0.0;
                for (int k = 0; k < 4; k++) s += S[r][k] * inv[k][3];
                rt[9 + r] = (float)s;
            }
        }
    }
    float* prm = ws + OFF_PRM;
    for (int o = 0; o < 16; o++) {
        float sc = g0[o] / sqrtf(v0[o] + 1e-5f);
        prm[o]      = w0[o] * sc;
        prm[16 + o] = b0[o] - m0[o] * sc;
    }
    for (int q = 0; q < 8; q++) {
        float sc = g1[q] / sqrtf(v1[q] + 1e-5f);
        for (int o = 0; o < 16; o++) prm[32 + q*16 + o] = w1[q*16 + o] * sc;
        prm[160 + q] = b1[q] - m1[q] * sc;
        prm[168 + q] = w2[q];
    }
    prm[176] = b2[0];
}

// ---------------- transpose features to (V,B,H,W,C) ----------------
__global__ __launch_bounds__(256) void transpose_kernel(const float* __restrict__ fea,
                                                        float* __restrict__ featT) {
    int t = blockIdx.x*256 + threadIdx.x;        // V*B*H*W
    int w = t % WW;
    int h = (t / WW) % HH;
    int b = (t / (WW*HH)) % BB;
    int v = t / (WW*HH*BB);
    const float* src = fea + (size_t)((v*BB + b)*CC) * HWp + h*WW + w;
    float* dst = featT + (size_t)((v*BB + b)*HWp + h*WW + w) * CC;
    #pragma unroll
    for (int c = 0; c < CC; c += 4) {
        float4 q;
        q.x = src[(c+0)*HWp];
        q.y = src[(c+1)*HWp];
        q.z = src[(c+2)*HWp];
        q.w = src[(c+3)*HWp];
        *reinterpret_cast<float4*>(dst + c) = q;
    }
}

__device__ __forceinline__ float half_max(float v) {
    v = fmaxf(v, __shfl_xor(v, 1));
    v = fmaxf(v, __shfl_xor(v, 2));
    v = fmaxf(v, __shfl_xor(v, 4));
    v = fmaxf(v, __shfl_xor(v, 8));
    v = fmaxf(v, __shfl_xor(v, 16));
    return v;
}

// MLP up to the final pre-sigmoid activation h2 (sigmoid applied after d-max,
// valid since sigmoid is monotone).
__device__ __forceinline__ float mlp_h2(const float* __restrict__ prm, float s) {
    float h0[16];
    #pragma unroll
    for (int o = 0; o < 16; o++) h0[o] = fmaxf(prm[o]*s + prm[16+o], 0.f);
    float h2 = prm[176];
    #pragma unroll
    for (int q = 0; q < 8; q++) {
        float a1 = prm[160+q];
        #pragma unroll
        for (int o = 0; o < 16; o++) a1 += prm[32+q*16+o]*h0[o];
        h2 += prm[168+q]*fmaxf(a1, 0.f);
    }
    return h2;
}

// ---------------- fused warp + sim + MLP + view aggregation ----------------
// block = 256 threads. Phase A: thread=(d=t>>3, chan-quad=t&7), loop over PX
// pixels; taps are single 128B lines shared by 8 sub-lanes. Phase B:
// thread=(pixel,d): MLP + d-max + sigmoid + aggregate across 4 views.
__global__ __launch_bounds__(256) void fused_sim_kernel(
    const float* __restrict__ featT, const float* __restrict__ rtAll,
    const float* __restrict__ prm, const float* __restrict__ depthv,
    float* __restrict__ simout, float* __restrict__ out) {
    __shared__ float simL[NV][DD][PX+1];    // padded: conflict-free
    __shared__ float depthL[DD][PX+1];

    int t = threadIdx.x;
    int dB  = t >> 3;     // 0..31 depth
    int sub = t & 7;      // channel quad
    int b = blockIdx.y;
    int pbase = blockIdx.x * PX;            // row-aligned segment (PX | WW)
    int hi  = pbase / WW;
    int wi0 = pbase % WW;
    float fy = (float)hi;

    // stage depth tile (32 d x PX)
    {
        int d = t >> 4, k = t & 15;
        depthL[d][k]      = depthv[(b*DD + d)*HWp + pbase + k];
        depthL[d+16][k]   = depthv[(b*DD + d+16)*HWp + pbase + k];
    }
    __syncthreads();

    // wave-uniform projection coefficients
    float rc[NV][12];
    #pragma unroll
    for (int v = 0; v < NV; v++)
        #pragma unroll
        for (int j = 0; j < 12; j++)
            rc[v][j] = rtAll[(b*NV + v)*12 + j];
    // per-view row bases: b*(fx) = rc0*fx + (rc1*fy + rc2); bx = fma(k+wi0, rc0, base)
    float bx0[NV], by0[NV], bz0[NV];
    #pragma unroll
    for (int v = 0; v < NV; v++) {
        bx0[v] = fmaf((float)wi0, rc[v][0], fmaf(fy, rc[v][1], rc[v][2]));
        by0[v] = fmaf((float)wi0, rc[v][3], fmaf(fy, rc[v][4], rc[v][5]));
        bz0[v] = fmaf((float)wi0, rc[v][6], fmaf(fy, rc[v][7], rc[v][8]));
    }

    #pragma unroll 2
    for (int k = 0; k < PX; k++) {
        int p = pbase + k;
        float fk = (float)k;
        float depth = depthL[dB][k];
        const float4 rv = *reinterpret_cast<const float4*>(
            featT + (size_t)(b*HWp + p)*CC + sub*4);

        #pragma unroll
        for (int v = 0; v < NV; v++) {
            float bx = fmaf(fk, rc[v][0], bx0[v]);
            float by = fmaf(fk, rc[v][3], by0[v]);
            float bz = fmaf(fk, rc[v][6], bz0[v]);
            float px = fmaf(bx, depth, rc[v][9]);
            float py = fmaf(by, depth, rc[v][10]);
            float pz = fmaf(bz, depth, rc[v][11]);
            float zi = __builtin_amdgcn_rcpf(pz);
            float sx = px * zi, sy = py * zi;
            float x0f = floorf(sx), y0f = floorf(sy);
            float wx1 = sx - x0f, wy1 = sy - y0f;
            float wx0 = 1.f - wx1, wy0 = 1.f - wy1;
            int xi0 = (int)x0f, yi0 = (int)y0f;     // saturating cvt
            int xi1 = xi0 + 1,  yi1 = yi0 + 1;
            float ax0 = ((unsigned)xi0 < WW) ? wx0 : 0.f;
            float ax1 = ((unsigned)xi1 < WW) ? wx1 : 0.f;
            float ay0 = ((unsigned)yi0 < HH) ? wy0 : 0.f;
            float ay1 = ((unsigned)yi1 < HH) ? wy1 : 0.f;
            int xc0 = min(max(xi0, 0), WW-1);
            int xc1 = min(max(xi1, 0), WW-1);
            int yc0 = min(max(yi0, 0), HH-1);
            int yc1 = min(max(yi1, 0), HH-1);
            const float* basep = featT + (size_t)(((v+1)*BB + b)*HWp)*CC + sub*4;
            int r0 = yc0*WW, r1 = yc1*WW;
            float4 t00 = *reinterpret_cast<const float4*>(basep + (size_t)(r0 + xc0)*CC);
            float4 t01 = *reinterpret_cast<const float4*>(basep + (size_t)(r0 + xc1)*CC);
            float4 t10 = *reinterpret_cast<const float4*>(basep + (size_t)(r1 + xc0)*CC);
            float4 t11 = *reinterpret_cast<const float4*>(basep + (size_t)(r1 + xc1)*CC);
            float w00 = ax0*ay0, w01 = ax1*ay0, w10 = ax0*ay1, w11 = ax1*ay1;
            float blx = fmaf(w11,t11.x, fmaf(w10,t10.x, fmaf(w01,t01.x, w00*t00.x)));
            float bly = fmaf(w11,t11.y, fmaf(w10,t10.y, fmaf(w01,t01.y, w00*t00.y)));
            float blz = fmaf(w11,t11.z, fmaf(w10,t10.z, fmaf(w01,t01.z, w00*t00.z)));
            float blw = fmaf(w11,t11.w, fmaf(w10,t10.w, fmaf(w01,t01.w, w00*t00.w)));
            float val = fmaf(rv.w,blw, fmaf(rv.z,blz, fmaf(rv.y,bly, rv.x*blx)));
            val += __shfl_xor(val, 1);
            val += __shfl_xor(val, 2);
            val += __shfl_xor(val, 4);
            if (sub == 0) simL[v][dB][k] = val * (1.f/(float)CC);
        }
    }
    __syncthreads();

    // ---- phase B: thread = (pixel p8, depth d2) ----
    int p8 = t >> 5;      // 0..7
    int d2 = t & 31;
    #pragma unroll
    for (int pi = 0; pi < PX/8; pi++) {
        int pidx = pi*8 + p8;
        int p = pbase + pidx;
        float s0 = simL[0][d2][pidx];
        float s1 = simL[1][d2][pidx];
        float s2 = simL[2][d2][pidx];
        float s3 = simL[3][d2][pidx];

        float m0 = half_max(mlp_h2(prm, s0));
        float m1 = half_max(mlp_h2(prm, s1));
        float m2 = half_max(mlp_h2(prm, s2));
        float m3 = half_max(mlp_h2(prm, s3));
        float vw0 = 1.f/(1.f + __expf(-m0));
        float vw1 = 1.f/(1.f + __expf(-m1));
        float vw2 = 1.f/(1.f + __expf(-m2));
        float vw3 = 1.f/(1.f + __expf(-m3));

        if (d2 == 0) out[OUT_VW + (b*NV + 0)*HWp + p] = vw0;
        if (d2 == 1) out[OUT_VW + (b*NV + 1)*HWp + p] = vw1;
        if (d2 == 2) out[OUT_VW + (b*NV + 2)*HWp + p] = vw2;
        if (d2 == 3) out[OUT_VW + (b*NV + 3)*HWp + p] = vw3;

        float wsum = 1e-5f + vw0 + vw1 + vw2 + vw3;
        float ssum = s0*vw0 + s1*vw1 + s2*vw2 + s3*vw3;
        simout[(b*DD + d2)*HWp + p] = ssum / wsum;
    }
}

// ---------------- 3x3x3 conv (SAME, zero pad) ----------------
__global__ __launch_bounds__(256) void conv_kernel(
    const float* __restrict__ sim, const float* __restrict__ rw,
    const float* __restrict__ rb, float* __restrict__ out) {
    int g = blockIdx.x*256 + threadIdx.x;   // B*D*HW
    int p = g % HWp;
    int dt = g / HWp;
    int d = dt % DD, b = dt / DD;
    int wi = p % WW, hi = p / WW;
    float acc = rb[0];
    #pragma unroll
    for (int kd = 0; kd < 3; kd++) {
        int dd2 = d + kd - 1;
        if (dd2 < 0 || dd2 >= DD) continue;
        #pragma unroll
        for (int kh = 0; kh < 3; kh++) {
            int hh2 = hi + kh - 1;
            if (hh2 < 0 || hh2 >= HH) continue;
            #pragma unroll
            for (int kw = 0; kw < 3; kw++) {
                int ww2 = wi + kw - 1;
                if (ww2 < 0 || ww2 >= WW) continue;
                acc += rw[(kd*3 + kh)*3 + kw] * sim[((b*DD + dd2)*HH + hh2)*WW + ww2];
            }
        }
    }
    out[OUT_COST + g] = acc;
}

// ---------------- softmax over D + argmax -> depth/conf/prob ----------------
__global__ __launch_bounds__(256) void softmax_kernel(
    const float* __restrict__ depthv, float* __restrict__ out) {
    int g = blockIdx.x*256 + threadIdx.x;   // B*HW
    int b = g / HWp, p = g % HWp;
    float c[DD];
    #pragma unroll
    for (int d = 0; d < DD; d++) c[d] = out[OUT_COST + (b*DD + d)*HWp + p];
    float m = c[0]; int bi = 0;
    #pragma unroll
    for (int d = 1; d < DD; d++) { if (c[d] > m) { m = c[d]; bi = d; } }
    float e[DD]; float sum = 0.f;
    #pragma unroll
    for (int d = 0; d < DD; d++) { e[d] = expf(c[d] - m); sum += e[d]; }
    float inv = 1.f / sum;
    #pragma unroll
    for (int d = 0; d < DD; d++) out[OUT_PROB + (b*DD + d)*HWp + p] = e[d] * inv;
    out[OUT_DEPTH + g] = depthv[(b*DD + bi)*HWp + p];
    out[OUT_CONF + g]  = inv;
}

extern "C" void kernel_launch(void* const* d_in, const int* in_sizes, int n_in,
                              void* d_out, int out_size, void* d_ws, size_t ws_size,
                              hipStream_t stream) {
    const float* features = (const float*)d_in[0];
    const float* proj     = (const float*)d_in[1];
    const float* depthv   = (const float*)d_in[2];
    const float* w0 = (const float*)d_in[4];
    const float* g0 = (const float*)d_in[5];
    const float* b0 = (const float*)d_in[6];
    const float* m0 = (const float*)d_in[7];
    const float* v0 = (const float*)d_in[8];
    const float* w1 = (const float*)d_in[9];
    const float* g1 = (const float*)d_in[10];
    const float* b1 = (const float*)d_in[11];
    const float* m1 = (const float*)d_in[12];
    const float* v1 = (const float*)d_in[13];
    const float* w2 = (const float*)d_in[14];
    const float* b2 = (const float*)d_in[15];
    const float* rw = (const float*)d_in[16];
    const float* rb = (const float*)d_in[17];
    float* out = (float*)d_out;
    float* ws  = (float*)d_ws;

    setup_kernel<<<1, 1, 0, stream>>>(proj, w0, g0, b0, m0, v0, w1, g1, b1, m1, v1, w2, b2, ws);
    transpose_kernel<<<VV*BB*HWp/256, 256, 0, stream>>>(features, ws + OFF_FEAT);

    fused_sim_kernel<<<dim3(HWp/PX, BB), 256, 0, stream>>>(
        ws + OFF_FEAT, ws + OFF_RT, ws + OFF_PRM, depthv,
        ws + OFF_SIM, out);

    conv_kernel<<<BB*DD*HWp/256, 256, 0, stream>>>(ws + OFF_SIM, rw, rb, out);
    softmax_kernel<<<BB*HWp/256, 256, 0, stream>>>(depthv, out);
}

// Round 5
// 169.419 us; speedup vs baseline: 3.4825x; 1.1633x over previous
//
#include <hip/hip_runtime.h>
#include <math.h>

#define BB 2
#define VV 5
#define CC 32
#define HH 128
#define WW 160
#define DD 32
#define HWp (HH*WW)          // 20480
#define NV (VV-1)            // 4 src views
#define PX 16                // pixels per block (divides WW)

// ---- workspace float offsets ----
#define OFF_RT   0                                   // B*NV*12 = 96
#define OFF_PRM  96                                  // 177 net params
#define OFF_FEAT 512                                 // V*B*HW*C = 6,553,600
#define OFF_SIM  (OFF_FEAT + VV*BB*HWp*CC)           // B*D*HW similarity

// ---- output float offsets (depth, conf, prob, cost_reg, view_weights) ----
#define OUT_DEPTH 0
#define OUT_CONF  (BB*HWp)
#define OUT_PROB  (2*BB*HWp)
#define OUT_COST  (OUT_PROB + BB*DD*HWp)
#define OUT_VW    (OUT_COST + BB*DD*HWp)

// ---------------- setup: projection matrices + folded BN params ----------------
__device__ void build_proj(const float* proj, int b, int v, double M[4][4]) {
    const float* E = proj + (((b*VV + v)*2 + 0)*16);
    const float* K = proj + (((b*VV + v)*2 + 1)*16);
    for (int r = 0; r < 3; r++)
        for (int c = 0; c < 4; c++) {
            double s = 0.0;
            for (int k = 0; k < 3; k++) s += (double)K[r*4+k] * (double)E[k*4+c];
            M[r][c] = s;
        }
    for (int c = 0; c < 4; c++) M[3][c] = (double)E[12+c];
}

__device__ void inv4(const double M[4][4], double out[4][4]) {
    double a[4][8];
    for (int i = 0; i < 4; i++)
        for (int j = 0; j < 4; j++) { a[i][j] = M[i][j]; a[i][4+j] = (i == j) ? 1.0 : 0.0; }
    for (int col = 0; col < 4; col++) {
        int piv = col; double best = fabs(a[col][col]);
        for (int r = col+1; r < 4; r++) if (fabs(a[r][col]) > best) { best = fabs(a[r][col]); piv = r; }
        if (piv != col) for (int j = 0; j < 8; j++) { double t = a[col][j]; a[col][j] = a[piv][j]; a[piv][j] = t; }
        double dinv = 1.0 / a[col][col];
        for (int j = 0; j < 8; j++) a[col][j] *= dinv;
        for (int r = 0; r < 4; r++) {
            if (r == col) continue;
            double f = a[r][col];
            for (int j = 0; j < 8; j++) a[r][j] -= f * a[col][j];
        }
    }
    for (int i = 0; i < 4; i++) for (int j = 0; j < 4; j++) out[i][j] = a[i][4+j];
}

__global__ void setup_kernel(const float* __restrict__ proj,
    const float* __restrict__ w0, const float* __restrict__ g0, const float* __restrict__ b0,
    const float* __restrict__ m0, const float* __restrict__ v0,
    const float* __restrict__ w1, const float* __restrict__ g1, const float* __restrict__ b1,
    const float* __restrict__ m1, const float* __restrict__ v1,
    const float* __restrict__ w2, const float* __restrict__ b2,
    float* __restrict__ ws) {
    if (threadIdx.x != 0 || blockIdx.x != 0) return;
    for (int b = 0; b < BB; b++) {
        double refM[4][4], inv[4][4];
        build_proj(proj, b, 0, refM);
        inv4(refM, inv);
        for (int v = 1; v < VV; v++) {
            double S[4][4]; build_proj(proj, b, v, S);
            float* rt = ws + OFF_RT + (b*NV + (v-1))*12;
            for (int r = 0; r < 3; r++) {
                for (int c = 0; c < 3; c++) {
                    double s = 0.0;
                    for (int k = 0; k < 4; k++) s += S[r][k] * inv[k][c];
                    rt[r*3 + c] = (float)s;
                }
                double s = 0.0;
                for (int k = 0; k < 4; k++) s += S[r][k] * inv[k][3];
                rt[9 + r] = (float)s;
            }
        }
    }
    float* prm = ws + OFF_PRM;
    for (int o = 0; o < 16; o++) {
        float sc = g0[o] / sqrtf(v0[o] + 1e-5f);
        prm[o]      = w0[o] * sc;
        prm[16 + o] = b0[o] - m0[o] * sc;
    }
    for (int q = 0; q < 8; q++) {
        float sc = g1[q] / sqrtf(v1[q] + 1e-5f);
        for (int o = 0; o < 16; o++) prm[32 + q*16 + o] = w1[q*16 + o] * sc;
        prm[160 + q] = b1[q] - m1[q] * sc;
        prm[168 + q] = w2[q];
    }
    prm[176] = b2[0];
}

// ---------------- transpose features to (V,B,H,W,C) ----------------
__global__ __launch_bounds__(256) void transpose_kernel(const float* __restrict__ fea,
                                                        float* __restrict__ featT) {
    int t = blockIdx.x*256 + threadIdx.x;        // V*B*H*W
    int w = t % WW;
    int h = (t / WW) % HH;
    int b = (t / (WW*HH)) % BB;
    int v = t / (WW*HH*BB);
    const float* src = fea + (size_t)((v*BB + b)*CC) * HWp + h*WW + w;
    float* dst = featT + (size_t)((v*BB + b)*HWp + h*WW + w) * CC;
    #pragma unroll
    for (int c = 0; c < CC; c += 4) {
        float4 q;
        q.x = src[(c+0)*HWp];
        q.y = src[(c+1)*HWp];
        q.z = src[(c+2)*HWp];
        q.w = src[(c+3)*HWp];
        *reinterpret_cast<float4*>(dst + c) = q;
    }
}

__device__ __forceinline__ float half_max(float v) {
    v = fmaxf(v, __shfl_xor(v, 1));
    v = fmaxf(v, __shfl_xor(v, 2));
    v = fmaxf(v, __shfl_xor(v, 4));
    v = fmaxf(v, __shfl_xor(v, 8));
    v = fmaxf(v, __shfl_xor(v, 16));
    return v;
}

// MLP up to the final pre-sigmoid activation h2 (sigmoid applied after d-max,
// valid since sigmoid is monotone).
__device__ __forceinline__ float mlp_h2(const float* __restrict__ prm, float s) {
    float h0[16];
    #pragma unroll
    for (int o = 0; o < 16; o++) h0[o] = fmaxf(prm[o]*s + prm[16+o], 0.f);
    float h2 = prm[176];
    #pragma unroll
    for (int q = 0; q < 8; q++) {
        float a1 = prm[160+q];
        #pragma unroll
        for (int o = 0; o < 16; o++) a1 += prm[32+q*16+o]*h0[o];
        h2 += prm[168+q]*fmaxf(a1, 0.f);
    }
    return h2;
}

// ---------------- fused warp + sim + MLP + view aggregation ----------------
// block = 256 threads. Phase A: thread = (pixel-parity kk=t>>7, depth d=(t>>2)&31,
// chan-octet sub=t&3); 2 pixels in flight, 4 threads/sim (8 channels each).
// Phase B: thread=(pixel,d): MLP + d-max + sigmoid + aggregate across 4 views.
__global__ __launch_bounds__(256) void fused_sim_kernel(
    const float* __restrict__ featT, const float* __restrict__ rtAll,
    const float* __restrict__ prm, const float* __restrict__ depthv,
    float* __restrict__ simout, float* __restrict__ out) {
    __shared__ float simL[NV][DD][PX+1];    // padded: conflict-free
    __shared__ float depthL[DD][PX+1];

    int t = threadIdx.x;
    int sub = t & 3;          // channel octet: channels sub*8 .. sub*8+7
    int dB  = (t >> 2) & 31;  // depth
    int kk  = t >> 7;         // pixel parity (0/1)
    int b = blockIdx.y;
    int pbase = blockIdx.x * PX;            // row-aligned segment (PX | WW)
    int hi  = pbase / WW;
    int wi0 = pbase % WW;
    float fy = (float)hi;

    // stage depth tile (32 d x PX)
    {
        int d = t >> 4, k = t & 15;
        depthL[d][k]      = depthv[(b*DD + d)*HWp + pbase + k];
        depthL[d+16][k]   = depthv[(b*DD + d+16)*HWp + pbase + k];
    }
    __syncthreads();

    // wave-uniform projection coefficients
    float rc[NV][12];
    #pragma unroll
    for (int v = 0; v < NV; v++)
        #pragma unroll
        for (int j = 0; j < 12; j++)
            rc[v][j] = rtAll[(b*NV + v)*12 + j];
    // per-view row bases
    float bx0[NV], by0[NV], bz0[NV];
    #pragma unroll
    for (int v = 0; v < NV; v++) {
        bx0[v] = fmaf((float)wi0, rc[v][0], fmaf(fy, rc[v][1], rc[v][2]));
        by0[v] = fmaf((float)wi0, rc[v][3], fmaf(fy, rc[v][4], rc[v][5]));
        bz0[v] = fmaf((float)wi0, rc[v][6], fmaf(fy, rc[v][7], rc[v][8]));
    }

    #pragma unroll 2
    for (int j = 0; j < PX/2; j++) {
        int kpix = j*2 + kk;
        int p = pbase + kpix;
        float fk = (float)kpix;
        float depth = depthL[dB][kpix];
        const float* refp = featT + (size_t)(b*HWp + p)*CC + sub*8;
        float4 rva = *reinterpret_cast<const float4*>(refp);
        float4 rvb = *reinterpret_cast<const float4*>(refp + 4);

        #pragma unroll
        for (int v = 0; v < NV; v++) {
            float bx = fmaf(fk, rc[v][0], bx0[v]);
            float by = fmaf(fk, rc[v][3], by0[v]);
            float bz = fmaf(fk, rc[v][6], bz0[v]);
            float px = fmaf(bx, depth, rc[v][9]);
            float py = fmaf(by, depth, rc[v][10]);
            float pz = fmaf(bz, depth, rc[v][11]);
            float zi = __builtin_amdgcn_rcpf(pz);
            float sx = px * zi, sy = py * zi;
            float x0f = floorf(sx), y0f = floorf(sy);
            float wx1 = sx - x0f, wy1 = sy - y0f;
            float wx0 = 1.f - wx1, wy0 = 1.f - wy1;
            int xi0 = (int)x0f, yi0 = (int)y0f;
            int xi1 = xi0 + 1,  yi1 = yi0 + 1;
            float ax0 = ((unsigned)xi0 < WW) ? wx0 : 0.f;
            float ax1 = ((unsigned)xi1 < WW) ? wx1 : 0.f;
            float ay0 = ((unsigned)yi0 < HH) ? wy0 : 0.f;
            float ay1 = ((unsigned)yi1 < HH) ? wy1 : 0.f;
            int xc0 = min(max(xi0, 0), WW-1);
            int xc1 = min(max(xi1, 0), WW-1);
            int yc0 = min(max(yi0, 0), HH-1);
            int yc1 = min(max(yi1, 0), HH-1);
            const float* basep = featT + (size_t)(((v+1)*BB + b)*HWp)*CC + sub*8;
            int r0 = yc0*WW, r1 = yc1*WW;
            const float* q00 = basep + (size_t)(r0 + xc0)*CC;
            const float* q01 = basep + (size_t)(r0 + xc1)*CC;
            const float* q10 = basep + (size_t)(r1 + xc0)*CC;
            const float* q11 = basep + (size_t)(r1 + xc1)*CC;
            float4 t00a = *reinterpret_cast<const float4*>(q00);
            float4 t00b = *reinterpret_cast<const float4*>(q00 + 4);
            float4 t01a = *reinterpret_cast<const float4*>(q01);
            float4 t01b = *reinterpret_cast<const float4*>(q01 + 4);
            float4 t10a = *reinterpret_cast<const float4*>(q10);
            float4 t10b = *reinterpret_cast<const float4*>(q10 + 4);
            float4 t11a = *reinterpret_cast<const float4*>(q11);
            float4 t11b = *reinterpret_cast<const float4*>(q11 + 4);
            float w00 = ax0*ay0, w01 = ax1*ay0, w10 = ax0*ay1, w11 = ax1*ay1;

            float blx, bly, blz, blw, acc;
            blx = fmaf(w11,t11a.x, fmaf(w10,t10a.x, fmaf(w01,t01a.x, w00*t00a.x)));
            bly = fmaf(w11,t11a.y, fmaf(w10,t10a.y, fmaf(w01,t01a.y, w00*t00a.y)));
            blz = fmaf(w11,t11a.z, fmaf(w10,t10a.z, fmaf(w01,t01a.z, w00*t00a.z)));
            blw = fmaf(w11,t11a.w, fmaf(w10,t10a.w, fmaf(w01,t01a.w, w00*t00a.w)));
            acc = fmaf(rva.w,blw, fmaf(rva.z,blz, fmaf(rva.y,bly, rva.x*blx)));
            blx = fmaf(w11,t11b.x, fmaf(w10,t10b.x, fmaf(w01,t01b.x, w00*t00b.x)));
            bly = fmaf(w11,t11b.y, fmaf(w10,t10b.y, fmaf(w01,t01b.y, w00*t00b.y)));
            blz = fmaf(w11,t11b.z, fmaf(w10,t10b.z, fmaf(w01,t01b.z, w00*t00b.z)));
            blw = fmaf(w11,t11b.w, fmaf(w10,t10b.w, fmaf(w01,t01b.w, w00*t00b.w)));
            acc = fmaf(rvb.w,blw, fmaf(rvb.z,blz, fmaf(rvb.y,bly, fmaf(rvb.x,blx, acc))));

            acc += __shfl_xor(acc, 1);
            acc += __shfl_xor(acc, 2);
            if (sub == 0) simL[v][dB][kpix] = acc * (1.f/(float)CC);
        }
    }
    __syncthreads();

    // ---- phase B: thread = (pixel p8, depth d2) ----
    int p8 = t >> 5;      // 0..7
    int d2 = t & 31;
    #pragma unroll
    for (int pi = 0; pi < PX/8; pi++) {
        int pidx = pi*8 + p8;
        int p = pbase + pidx;
        float s0 = simL[0][d2][pidx];
        float s1 = simL[1][d2][pidx];
        float s2 = simL[2][d2][pidx];
        float s3 = simL[3][d2][pidx];

        float m0 = half_max(mlp_h2(prm, s0));
        float m1 = half_max(mlp_h2(prm, s1));
        float m2 = half_max(mlp_h2(prm, s2));
        float m3 = half_max(mlp_h2(prm, s3));
        float vw0 = 1.f/(1.f + __expf(-m0));
        float vw1 = 1.f/(1.f + __expf(-m1));
        float vw2 = 1.f/(1.f + __expf(-m2));
        float vw3 = 1.f/(1.f + __expf(-m3));

        if (d2 == 0) out[OUT_VW + (b*NV + 0)*HWp + p] = vw0;
        if (d2 == 1) out[OUT_VW + (b*NV + 1)*HWp + p] = vw1;
        if (d2 == 2) out[OUT_VW + (b*NV + 2)*HWp + p] = vw2;
        if (d2 == 3) out[OUT_VW + (b*NV + 3)*HWp + p] = vw3;

        float wsum = 1e-5f + vw0 + vw1 + vw2 + vw3;
        float ssum = s0*vw0 + s1*vw1 + s2*vw2 + s3*vw3;
        simout[(b*DD + d2)*HWp + p] = ssum / wsum;
    }
}

// ---------------- 3x3x3 conv (SAME, zero pad) ----------------
__global__ __launch_bounds__(256) void conv_kernel(
    const float* __restrict__ sim, const float* __restrict__ rw,
    const float* __restrict__ rb, float* __restrict__ out) {
    int g = blockIdx.x*256 + threadIdx.x;   // B*D*HW
    int p = g % HWp;
    int dt = g / HWp;
    int d = dt % DD, b = dt / DD;
    int wi = p % WW, hi = p / WW;
    float acc = rb[0];
    #pragma unroll
    for (int kd = 0; kd < 3; kd++) {
        int dd2 = d + kd - 1;
        if (dd2 < 0 || dd2 >= DD) continue;
        #pragma unroll
        for (int kh = 0; kh < 3; kh++) {
            int hh2 = hi + kh - 1;
            if (hh2 < 0 || hh2 >= HH) continue;
            #pragma unroll
            for (int kw = 0; kw < 3; kw++) {
                int ww2 = wi + kw - 1;
                if (ww2 < 0 || ww2 >= WW) continue;
                acc += rw[(kd*3 + kh)*3 + kw] * sim[((b*DD + dd2)*HH + hh2)*WW + ww2];
            }
        }
    }
    out[OUT_COST + g] = acc;
}

// ---------------- softmax over D + argmax -> depth/conf/prob ----------------
__global__ __launch_bounds__(256) void softmax_kernel(
    const float* __restrict__ depthv, float* __restrict__ out) {
    int g = blockIdx.x*256 + threadIdx.x;   // B*HW
    int b = g / HWp, p = g % HWp;
    float c[DD];
    #pragma unroll
    for (int d = 0; d < DD; d++) c[d] = out[OUT_COST + (b*DD + d)*HWp + p];
    float m = c[0]; int bi = 0;
    #pragma unroll
    for (int d = 1; d < DD; d++) { if (c[d] > m) { m = c[d]; bi = d; } }
    float e[DD]; float sum = 0.f;
    #pragma unroll
    for (int d = 0; d < DD; d++) { e[d] = expf(c[d] - m); sum += e[d]; }
    float inv = 1.f / sum;
    #pragma unroll
    for (int d = 0; d < DD; d++) out[OUT_PROB + (b*DD + d)*HWp + p] = e[d] * inv;
    out[OUT_DEPTH + g] = depthv[(b*DD + bi)*HWp + p];
    out[OUT_CONF + g]  = inv;
}

extern "C" void kernel_launch(void* const* d_in, const int* in_sizes, int n_in,
                              void* d_out, int out_size, void* d_ws, size_t ws_size,
                              hipStream_t stream) {
    const float* features = (const float*)d_in[0];
    const float* proj     = (const float*)d_in[1];
    const float* depthv   = (const float*)d_in[2];
    const float* w0 = (const float*)d_in[4];
    const float* g0 = (const float*)d_in[5];
    const float* b0 = (const float*)d_in[6];
    const float* m0 = (const float*)d_in[7];
    const float* v0 = (const float*)d_in[8];
    const float* w1 = (const float*)d_in[9];
    const float* g1 = (const float*)d_in[10];
    const float* b1 = (const float*)d_in[11];
    const float* m1 = (const float*)d_in[12];
    const float* v1 = (const float*)d_in[13];
    const float* w2 = (const float*)d_in[14];
    const float* b2 = (const float*)d_in[15];
    const float* rw = (const float*)d_in[16];
    const float* rb = (const float*)d_in[17];
    float* out = (float*)d_out;
    float* ws  = (float*)d_ws;

    setup_kernel<<<1, 1, 0, stream>>>(proj, w0, g0, b0, m0, v0, w1, g1, b1, m1, v1, w2, b2, ws);
    transpose_kernel<<<VV*BB*HWp/256, 256, 0, stream>>>(features, ws + OFF_FEAT);

    fused_sim_kernel<<<dim3(HWp/PX, BB), 256, 0, stream>>>(
        ws + OFF_FEAT, ws + OFF_RT, ws + OFF_PRM, depthv,
        ws + OFF_SIM, out);

    conv_kernel<<<BB*DD*HWp/256, 256, 0, stream>>>(ws + OFF_SIM, rw, rb, out);
    softmax_kernel<<<BB*HWp/256, 256, 0, stream>>>(depthv, out);
}